// Round 2
// baseline (2260.846 us; speedup 1.0000x reference)
//
#include <hip/hip_runtime.h>

using bf = unsigned short;
typedef __attribute__((ext_vector_type(8))) short short8v;
typedef __attribute__((ext_vector_type(4))) float f32x4;
typedef __attribute__((ext_vector_type(4))) unsigned int u32x4;
typedef __attribute__((ext_vector_type(2))) unsigned int u32x2;

__device__ __forceinline__ float bf2f(bf u) { return __uint_as_float(((unsigned)u) << 16); }
__device__ __forceinline__ bf f2bf(float f) {
    unsigned x = __float_as_uint(f);
    x += 0x7fffu + ((x >> 16) & 1u);   // RNE (finite values only)
    return (bf)(x >> 16);
}

// ---------------------------------------------------------------------------
// Implicit-GEMM conv, NHWC bf16, fp32 accum.
//  M = co (tile 64), N = pixels (tile 128), K = Ci*RS*RS.
//  A (weights) packed [chunk][tap j][co][ci_in_chunk] -> 16B contiguous frags.
//  B (activations) staged in LDS [in_row][in_col][ci_chunk] with halo + zero pad,
//  ci 16B-granule XOR-swizzled by column to avoid 128B-stride bank conflicts.
//  mfma_f32_16x16x32_bf16 lane maps: A row=l&15,k=8*(l>>4)+i ; B col=l&15,same k ;
//  D col(l&15)=pixel, row((l>>4)*4+i)=co.
// COMBINE: fused  y = m ? relu(acc + bias + res) : res  (m==0 blocks exit early).
// Y == res is safe: each thread reads res[off] then writes Y[off] itself.
// ---------------------------------------------------------------------------
template <int CC, int RS, int STRIDE, bool RELU, bool COMBINE, int LOG2W>
__global__ __launch_bounds__(256) void conv_mfma(
    const bf* __restrict__ X, const bf* __restrict__ Wp,
    const float* __restrict__ bias, bf* __restrict__ Y,
    const bf* __restrict__ res, const float* __restrict__ probs,
    int kidx, int Ci, int Co) {
    constexpr int W = 1 << LOG2W;
    constexpr int ROWS = 128 >> LOG2W;
    constexpr int PAD = (RS == 3) ? 1 : 0;
    constexpr int IN_ROWS = (ROWS - 1) * STRIDE + RS;
    constexpr int IN_COLS = (W - 1) * STRIDE + RS;
    constexpr int NG = CC / 8;
    constexpr int HIN = W * STRIDE;
    constexpr int RSRS = RS * RS;

    __shared__ bf sX[IN_ROWS * IN_COLS * CC];

    const int tid = threadIdx.x;
    const int n = blockIdx.z;
    const int coBase = blockIdx.y << 6;
    const int r0 = blockIdx.x * ROWS;
    const size_t pixBase = (size_t)n * W * W + (size_t)r0 * W;  // tile pixels contiguous

    bool active = true;
    if (kidx >= 0) active = (probs[n * 15 + kidx] >= 0.5f);
    if (!active) {
        if constexpr (COMBINE) {
            for (int i = tid; i < (128 * 64) / 8; i += 256) {
                int lp = i >> 3;
                int c8 = (i & 7) * 8;
                size_t off = (pixBase + lp) * Co + coBase + c8;
                u32x4 v = *reinterpret_cast<const u32x4*>(res + off);
                *reinterpret_cast<u32x4*>(Y + off) = v;
            }
        }
        return;
    }

    const int lane = tid & 63;
    const int wid = tid >> 6;
    const int l15 = lane & 15;
    const int lq = lane >> 4;
    const int wm = wid >> 1;  // co half (0..1)
    const int wn = wid & 1;   // pixel half (0..1)

    f32x4 acc[2][4] = {};

    int prow[4], pcol[4];
#pragma unroll
    for (int nf = 0; nf < 4; ++nf) {
        int p = wn * 64 + nf * 16 + l15;
        prow[nf] = p >> LOG2W;
        pcol[nf] = p & (W - 1);
    }

    const bf* Xn = X + (size_t)n * HIN * HIN * Ci;
    const int NCH = Ci / CC;

    for (int ch = 0; ch < NCH; ++ch) {
        if (ch) __syncthreads();
        constexpr int TG = IN_ROWS * IN_COLS * NG;
        for (int g = tid; g < TG; g += 256) {
            int ir = g / (IN_COLS * NG);
            int rem = g - ir * (IN_COLS * NG);
            int ic = rem / NG;
            int gc = rem - ic * NG;
            int in_r = r0 * STRIDE - PAD + ir;
            int in_c = ic - PAD;
            u32x4 v = {0, 0, 0, 0};
            if ((unsigned)in_r < (unsigned)HIN && (unsigned)in_c < (unsigned)HIN) {
                v = *reinterpret_cast<const u32x4*>(
                    Xn + ((size_t)in_r * HIN + in_c) * Ci + ch * CC + gc * 8);
            }
            int gsw = gc ^ (ic & (NG - 1));
            *reinterpret_cast<u32x4*>(&sX[((ir * IN_COLS + ic) * NG + gsw) * 8]) = v;
        }
        __syncthreads();

        if constexpr (CC >= 32) {
#pragma unroll
            for (int j = 0; j < RSRS; ++j) {
                const int dh = j / RS;
                const int dw = j % RS;
#pragma unroll
                for (int kk = 0; kk < CC / 32; ++kk) {
                    short8v a[2];
#pragma unroll
                    for (int mf = 0; mf < 2; ++mf) {
                        int co = coBase + wm * 32 + mf * 16 + l15;
                        a[mf] = *reinterpret_cast<const short8v*>(
                            Wp + (((size_t)(ch * RSRS + j) * Co + co) * CC + kk * 32 + lq * 8));
                    }
                    short8v b[4];
#pragma unroll
                    for (int nf = 0; nf < 4; ++nf) {
                        int ir = prow[nf] * STRIDE + dh;
                        int ic = pcol[nf] * STRIDE + dw;
                        int gk = (kk * 4 + lq) ^ (ic & (NG - 1));
                        b[nf] = *reinterpret_cast<const short8v*>(
                            &sX[((ir * IN_COLS + ic) * NG + gk) * 8]);
                    }
#pragma unroll
                    for (int mf = 0; mf < 2; ++mf)
#pragma unroll
                        for (int nf = 0; nf < 4; ++nf)
                            acc[mf][nf] = __builtin_amdgcn_mfma_f32_16x16x32_bf16(
                                a[mf], b[nf], acc[mf][nf], 0, 0, 0);
                }
            }
        } else {
            // CC==8 (seed conv): K padded 72->96; per-lane tap j = kt*4 + (lane>>4)
#pragma unroll
            for (int kt = 0; kt < 3; ++kt) {
                int j = kt * 4 + lq;
                int jj = (j < 9) ? j : 0;  // padded taps read tap0 data, zero weights
                int dh = jj / 3, dw = jj % 3;
                short8v a[2];
#pragma unroll
                for (int mf = 0; mf < 2; ++mf) {
                    int co = coBase + wm * 32 + mf * 16 + l15;
                    a[mf] = *reinterpret_cast<const short8v*>(Wp + ((size_t)j * Co + co) * 8);
                }
                short8v b[4];
#pragma unroll
                for (int nf = 0; nf < 4; ++nf) {
                    int ir = prow[nf] + dh;
                    int ic = pcol[nf] + dw;
                    b[nf] = *reinterpret_cast<const short8v*>(&sX[(ir * IN_COLS + ic) * 8]);
                }
#pragma unroll
                for (int mf = 0; mf < 2; ++mf)
#pragma unroll
                    for (int nf = 0; nf < 4; ++nf)
                        acc[mf][nf] = __builtin_amdgcn_mfma_f32_16x16x32_bf16(
                            a[mf], b[nf], acc[mf][nf], 0, 0, 0);
            }
        }
    }

    // epilogue: bias (+res, relu, mask), store NHWC bf16
#pragma unroll
    for (int mf = 0; mf < 2; ++mf) {
        int co0 = coBase + wm * 32 + mf * 16 + lq * 4;
        float4 b4 = *reinterpret_cast<const float4*>(bias + co0);
        float bb[4] = {b4.x, b4.y, b4.z, b4.w};
#pragma unroll
        for (int nf = 0; nf < 4; ++nf) {
            int p = wn * 64 + nf * 16 + l15;
            size_t off = (pixBase + p) * Co + co0;
            float v[4];
#pragma unroll
            for (int i = 0; i < 4; ++i) v[i] = acc[mf][nf][i] + bb[i];
            if constexpr (COMBINE) {
                u32x2 r2 = *reinterpret_cast<const u32x2*>(res + off);
                bf rr[4] = {(bf)(r2[0] & 0xffff), (bf)(r2[0] >> 16),
                            (bf)(r2[1] & 0xffff), (bf)(r2[1] >> 16)};
#pragma unroll
                for (int i = 0; i < 4; ++i) v[i] = fmaxf(v[i] + bf2f(rr[i]), 0.f);
            }
            if constexpr (RELU) {
#pragma unroll
                for (int i = 0; i < 4; ++i) v[i] = fmaxf(v[i], 0.f);
            }
            unsigned lo = (unsigned)f2bf(v[0]) | ((unsigned)f2bf(v[1]) << 16);
            unsigned hi = (unsigned)f2bf(v[2]) | ((unsigned)f2bf(v[3]) << 16);
            u32x2 o2 = {lo, hi};
            *reinterpret_cast<u32x2*>(Y + off) = o2;
        }
    }
}

// OIHW fp32 -> packed [chunk][tap][co][ci_in_chunk] bf16 (zero-padded)
__global__ void repack_k(const float* __restrict__ w, bf* __restrict__ wp,
                         int Co, int Ci, int RSRS, int CC, int JPAD, size_t total) {
    size_t idx = (size_t)blockIdx.x * 256 + threadIdx.x;
    if (idx >= total) return;
    int cw = (int)(idx % CC);
    int co = (int)((idx / CC) % Co);
    int j = (int)((idx / ((size_t)CC * Co)) % JPAD);
    int ch = (int)(idx / ((size_t)CC * Co * JPAD));
    int ci = ch * CC + cw;
    float v = 0.f;
    if (ci < Ci && j < RSRS) v = w[((size_t)co * Ci + ci) * RSRS + j];
    wp[idx] = f2bf(v);
}

// NCHW fp32 [128,3,64,64] -> NHWC bf16 [128,64,64,8] (channels zero-padded to 8)
__global__ void cvt_in(const float* __restrict__ in, bf* __restrict__ out) {
    size_t idx = (size_t)blockIdx.x * 256 + threadIdx.x;  // 128*64*64*8
    int c = (int)(idx & 7);
    size_t pix = idx >> 3;
    int w = (int)(pix & 63);
    int h = (int)((pix >> 6) & 63);
    int n = (int)(pix >> 12);
    float v = 0.f;
    if (c < 3) v = in[(((size_t)n * 3 + c) * 64 + h) * 64 + w];
    out[idx] = f2bf(v);
}

// [NB,16,16,256] bf16 -> mean over 256 pixels -> [NB,256] f32
__global__ void pool_k(const bf* __restrict__ X, float* __restrict__ pooled) {
    int n = blockIdx.x;
    int co = threadIdx.x;
    float s = 0.f;
    for (int p = 0; p < 256; ++p) s += bf2f(X[((size_t)n * 256 + p) * 256 + co]);
    pooled[n * 256 + co] = s * (1.f / 256.f);
}

// out[n,o] = pooled[n,:] . fc_w[o,:] + fc_b[o]   (fp32)
__global__ void fc_k(const float* __restrict__ pooled, const float* __restrict__ fw,
                     const float* __restrict__ fb, float* __restrict__ out) {
    __shared__ float sp[256];
    int n = blockIdx.x;
    sp[threadIdx.x] = pooled[n * 256 + threadIdx.x];
    __syncthreads();
    for (int o = threadIdx.x; o < 1000; o += 256) {
        float acc = fb[o];
        for (int k = 0; k < 256; ++k) acc += sp[k] * fw[(size_t)o * 256 + k];
        out[(size_t)n * 1000 + o] = acc;
    }
}

// ---------------------------------------------------------------------------
// One group: ds: X->OUT ; conv1: X->H ; conv2: (H,OUT)->OUT in-place;
// then 4 identity blocks: conv1: OUT->H ; conv2: (H,OUT)->OUT in-place.
// CC1: channel-chunk for conv1 (32 for stride-2 variants to keep LDS < 64KB).
template <int S, int LW, int CC1>
static void run_group(hipStream_t st, bf* X, bf* H, bf* OUT,
                      bf* wp_ds, const float* ds_b, bf* wp_w1, const float* b1,
                      bf* wp_w2, const float* b2, bf* const* wp_rw1, const float* rb1,
                      bf* const* wp_rw2, const float* rb2, const float* probs_c,
                      int kbase, int Ci, int Co, int NB) {
    constexpr int Wo = 1 << LW;
    dim3 grid((Wo * Wo) / 128, Co / 64, NB);
    conv_mfma<64, 1, S, false, false, LW><<<grid, 256, 0, st>>>(
        X, wp_ds, ds_b, OUT, nullptr, nullptr, -1, Ci, Co);
    conv_mfma<CC1, 3, S, true, false, LW><<<grid, 256, 0, st>>>(
        X, wp_w1, b1, H, nullptr, probs_c, kbase, Ci, Co);
    conv_mfma<64, 3, 1, false, true, LW><<<grid, 256, 0, st>>>(
        H, wp_w2, b2, OUT, OUT, probs_c, kbase, Co, Co);
    for (int j = 0; j < 4; ++j) {
        conv_mfma<64, 3, 1, true, false, LW><<<grid, 256, 0, st>>>(
            OUT, wp_rw1[j], rb1 + j * Co, H, nullptr, probs_c, kbase + 1 + j, Co, Co);
        conv_mfma<64, 3, 1, false, true, LW><<<grid, 256, 0, st>>>(
            H, wp_rw2[j], rb2 + j * Co, OUT, OUT, probs_c, kbase + 1 + j, Co, Co);
    }
}

extern "C" void kernel_launch(void* const* d_in, const int* in_sizes, int n_in,
                              void* d_out, int out_size, void* d_ws, size_t ws_size,
                              hipStream_t stream) {
    const float* input = (const float*)d_in[0];
    const float* probs = (const float*)d_in[1];
    const float* seed_w = (const float*)d_in[2];
    const float* seed_b = (const float*)d_in[3];
    const float* fc_w = (const float*)d_in[34];
    const float* fc_b = (const float*)d_in[35];

    char* pw = (char*)d_ws;
    auto alloc = [&](size_t bytes) -> void* {
        void* r = (void*)pw;
        pw += ((bytes + 255) & ~(size_t)255);
        return r;
    };

    // ---- persistent (batch-wide) allocations first ----
    bf* xin = (bf*)alloc(128ull * 64 * 64 * 8 * 2);        // 8 MB
    float* pooled = (float*)alloc(128 * 256 * 4);

    auto pack = [&](const float* w, int Co_, int Ci_, int RSRS_, int CC_, int JPAD_) -> bf* {
        int NCH_ = (Ci_ + CC_ - 1) / CC_;
        size_t total = (size_t)NCH_ * JPAD_ * Co_ * CC_;
        bf* wp = (bf*)alloc(total * 2);
        repack_k<<<dim3((unsigned)((total + 255) / 256)), 256, 0, stream>>>(
            w, wp, Co_, Ci_, RSRS_, CC_, JPAD_, total);
        return wp;
    };

    cvt_in<<<dim3(16384), 256, 0, stream>>>(input, xin);

    bf* wpSeed = pack(seed_w, 64, 3, 9, 8, 12);
    const int cis[3] = {64, 64, 128};
    const int cos[3] = {64, 128, 256};
    const int cc1s[3] = {64, 32, 32};  // conv1 channel-chunk (stride-2 -> 32)
    bf* wp_ds[3];
    bf* wp_w1[3];
    bf* wp_w2[3];
    bf* wp_rw1[3][4];
    bf* wp_rw2[3][4];
    const float *ds_b[3], *b1[3], *b2[3], *rb1[3], *rb2[3];
    for (int g = 0; g < 3; ++g) {
        int base = 4 + g * 10;
        const float* dsw = (const float*)d_in[base + 0];
        ds_b[g] = (const float*)d_in[base + 1];
        const float* w1 = (const float*)d_in[base + 2];
        b1[g] = (const float*)d_in[base + 3];
        const float* w2 = (const float*)d_in[base + 4];
        b2[g] = (const float*)d_in[base + 5];
        const float* rw1 = (const float*)d_in[base + 6];
        rb1[g] = (const float*)d_in[base + 7];
        const float* rw2 = (const float*)d_in[base + 8];
        rb2[g] = (const float*)d_in[base + 9];
        int Ci = cis[g], Co = cos[g];
        wp_ds[g] = pack(dsw, Co, Ci, 1, 64, 1);
        wp_w1[g] = pack(w1, Co, Ci, 9, cc1s[g], 9);
        wp_w2[g] = pack(w2, Co, Co, 9, 64, 9);
        for (int j = 0; j < 4; ++j) {
            wp_rw1[g][j] = pack(rw1 + (size_t)j * Co * Co * 9, Co, Co, 9, 64, 9);
            wp_rw2[g][j] = pack(rw2 + (size_t)j * Co * Co * 9, Co, Co, 9, 64, 9);
        }
    }

    // ---- choose batch chunk NB so 3 activation buffers fit remaining ws ----
    size_t used = (size_t)(pw - (char*)d_ws);
    size_t avail = (ws_size > used) ? (ws_size - used) : 0;
    const size_t PER_IMG = 64ull * 64 * 64 * 2;  // 512 KB (largest stage)
    int NB = 128;
    while (NB > 8 && (size_t)3 * NB * PER_IMG + 4096 > avail) NB >>= 1;

    bf* A = (bf*)alloc((size_t)NB * PER_IMG);
    bf* Bb = (bf*)alloc((size_t)NB * PER_IMG);
    bf* C = (bf*)alloc((size_t)NB * PER_IMG);

    for (int n0 = 0; n0 < 128; n0 += NB) {
        const float* pc = probs + (size_t)n0 * 15;
        // seed conv (+relu): [NB,64,64,8] -> [NB,64,64,64] in A
        conv_mfma<8, 3, 1, true, false, 6><<<dim3(32, 1, NB), 256, 0, stream>>>(
            xin + (size_t)n0 * 64 * 64 * 8, wpSeed, seed_b, A, nullptr, nullptr, -1, 8, 64);

        run_group<1, 6, 64>(stream, A, Bb, C, wp_ds[0], ds_b[0], wp_w1[0], b1[0],
                            wp_w2[0], b2[0], wp_rw1[0], rb1[0], wp_rw2[0], rb2[0],
                            pc, 0, 64, 64, NB);
        run_group<2, 5, 32>(stream, C, Bb, A, wp_ds[1], ds_b[1], wp_w1[1], b1[1],
                            wp_w2[1], b2[1], wp_rw1[1], rb1[1], wp_rw2[1], rb2[1],
                            pc, 5, 64, 128, NB);
        run_group<2, 4, 32>(stream, A, Bb, C, wp_ds[2], ds_b[2], wp_w1[2], b1[2],
                            wp_w2[2], b2[2], wp_rw1[2], rb1[2], wp_rw2[2], rb2[2],
                            pc, 10, 128, 256, NB);

        pool_k<<<dim3(NB), 256, 0, stream>>>(C, pooled + (size_t)n0 * 256);
    }

    fc_k<<<dim3(128), 256, 0, stream>>>(pooled, fc_w, fc_b, (float*)d_out);
}